// Round 3
// baseline (51.428 us; speedup 1.0000x reference)
//
#include <hip/hip_runtime.h>

// Welford mean/variance over batch dim.
// x: (B=64, C=64, H=128, W=128) fp32; m0,s0: (C,H,W) fp32; n0: int scalar.
// out: (2, C, H, W) fp32 = [m; s].

#define B_DIM 64
#define CHW (64 * 128 * 128)   // 1,048,576

typedef float f32x4 __attribute__((ext_vector_type(4)));  // native vector: nt-builtin-compatible

__global__ __launch_bounds__(256) void welford_kernel(
    const float* __restrict__ x,
    const float* __restrict__ m0,
    const float* __restrict__ s0,
    const int* __restrict__ n0p,
    float* __restrict__ out)
{
    const int t = blockIdx.x * blockDim.x + threadIdx.x;  // float4 column index
    const int stride4 = CHW / 4;
    if (t >= stride4) return;

    const f32x4* __restrict__ x4 = (const f32x4*)x;
    f32x4 m = ((const f32x4*)m0)[t];
    f32x4 s = ((const f32x4*)s0)[t];
    float n = (float)(*n0p);   // wave-uniform scalar load

    // x is streamed exactly once (256 MB == L3 size) -> nontemporal loads
    // keep it from evicting everything else and skip the cache-fill cost.
    #pragma unroll 8
    for (int b = 0; b < B_DIM; ++b) {
        f32x4 xi = __builtin_nontemporal_load(&x4[b * stride4 + t]);
        float inv = 1.0f / (n + 1.0f);   // same expression order as R1 (absmax 0.0)
        #pragma unroll
        for (int j = 0; j < 4; ++j) {
            float d = xi[j] - m[j];
            m[j] += d * inv;
            s[j] += (xi[j] - m[j]) * d;
        }
        n += 1.0f;
    }

    f32x4* out4 = (f32x4*)out;
    __builtin_nontemporal_store(m, &out4[t]);            // mean block
    __builtin_nontemporal_store(s, &out4[stride4 + t]);  // M2 block
}

extern "C" void kernel_launch(void* const* d_in, const int* in_sizes, int n_in,
                              void* d_out, int out_size, void* d_ws, size_t ws_size,
                              hipStream_t stream) {
    const float* x  = (const float*)d_in[0];
    const float* m0 = (const float*)d_in[1];
    const float* s0 = (const float*)d_in[2];
    const int*   n0 = (const int*)d_in[3];
    float* out = (float*)d_out;

    const int cols4 = CHW / 4;           // 262,144 float4 columns
    const int block = 256;
    const int grid = (cols4 + block - 1) / block;  // 1024 blocks -> 16 waves/CU
    welford_kernel<<<grid, block, 0, stream>>>(x, m0, s0, n0, out);
}

// Round 4
// 51.178 us; speedup vs baseline: 1.0049x; 1.0049x over previous
//
#include <hip/hip_runtime.h>

// Welford mean/variance over batch dim.
// x: (B=64, C=64, H=128, W=128) fp32; m0,s0: (C,H,W) fp32; n0: int scalar.
// out: (2, C, H, W) fp32 = [m; s].

#define B_DIM 64
#define CHW (64 * 128 * 128)   // 1,048,576

typedef float f32x4 __attribute__((ext_vector_type(4)));

__global__ __launch_bounds__(256) void welford_kernel(
    const float* __restrict__ x,
    const float* __restrict__ m0,
    const float* __restrict__ s0,
    const int* __restrict__ n0p,
    float* __restrict__ out)
{
    const int t = blockIdx.x * blockDim.x + threadIdx.x;  // float4 column index
    const int stride4 = CHW / 4;
    if (t >= stride4) return;

    const f32x4* __restrict__ x4 = (const f32x4*)x;
    f32x4 m = ((const f32x4*)m0)[t];
    f32x4 s = ((const f32x4*)s0)[t];
    float n = (float)(*n0p);   // wave-uniform scalar load

    // Plain (cached) loads: R3 showed nontemporal loads regress 4%.
    // unroll 16 -> 16 independent loads in flight per wave so the serial
    // Welford chain's vmcnt waits overlap with next-batch load issue.
    #pragma unroll 16
    for (int b = 0; b < B_DIM; ++b) {
        f32x4 xi = x4[b * stride4 + t];
        float inv = 1.0f / (n + 1.0f);   // exact fp32 division (absmax 0.0 in R1/R3)
        #pragma unroll
        for (int j = 0; j < 4; ++j) {
            float d = xi[j] - m[j];
            m[j] += d * inv;
            s[j] += (xi[j] - m[j]) * d;
        }
        n += 1.0f;
    }

    // Output is write-once, no reuse: nontemporal store skips L2 allocation.
    f32x4* out4 = (f32x4*)out;
    __builtin_nontemporal_store(m, &out4[t]);            // mean block
    __builtin_nontemporal_store(s, &out4[stride4 + t]);  // M2 block
}

extern "C" void kernel_launch(void* const* d_in, const int* in_sizes, int n_in,
                              void* d_out, int out_size, void* d_ws, size_t ws_size,
                              hipStream_t stream) {
    const float* x  = (const float*)d_in[0];
    const float* m0 = (const float*)d_in[1];
    const float* s0 = (const float*)d_in[2];
    const int*   n0 = (const int*)d_in[3];
    float* out = (float*)d_out;

    const int cols4 = CHW / 4;           // 262,144 float4 columns
    const int block = 256;
    const int grid = (cols4 + block - 1) / block;  // 1024 blocks -> 16 waves/CU
    welford_kernel<<<grid, block, 0, stream>>>(x, m0, s0, n0, out);
}

// Round 5
// 47.020 us; speedup vs baseline: 1.0938x; 1.0884x over previous
//
#include <hip/hip_runtime.h>

// Welford mean/variance over batch dim.
// x: (B=64, C=64, H=128, W=128) fp32; m0,s0: (C,H,W) fp32; n0: int scalar.
// out: (2, C, H, W) fp32 = [m; s].

#define B_DIM 64
#define CHW (64 * 128 * 128)   // 1,048,576

typedef float f32x4 __attribute__((ext_vector_type(4)));

__global__ __launch_bounds__(256) void welford_kernel(
    const float* __restrict__ x,
    const float* __restrict__ m0,
    const float* __restrict__ s0,
    const int* __restrict__ n0p,
    float* __restrict__ out)
{
    // Each thread owns 2 ADJACENT float4 columns -> each wave loads 2 KB
    // contiguous per b-step (vs 1 KB in R1): fewer, wider address streams
    // for better HBM page locality; and 2 independent Welford chains (ILP).
    const int t = blockIdx.x * blockDim.x + threadIdx.x;   // pair index
    const int stride4 = CHW / 4;                           // 262,144 float4 cols
    const int c0 = 2 * t;                                  // first float4 col
    if (c0 >= stride4) return;

    const f32x4* __restrict__ x4 = (const f32x4*)x;
    f32x4 ma = ((const f32x4*)m0)[c0];
    f32x4 mb = ((const f32x4*)m0)[c0 + 1];
    f32x4 sa = ((const f32x4*)s0)[c0];
    f32x4 sb = ((const f32x4*)s0)[c0 + 1];
    float n = (float)(*n0p);   // wave-uniform scalar load

    #pragma unroll 4
    for (int b = 0; b < B_DIM; ++b) {
        f32x4 xa = x4[b * stride4 + c0];
        f32x4 xb = x4[b * stride4 + c0 + 1];
        // 1-ulp reciprocal instead of exact div: threshold is 2.6, this costs
        // ~1e-7 relative per step; cuts ~10 VALU ops to 1 per b-step.
        float inv = __builtin_amdgcn_rcpf(n + 1.0f);
        #pragma unroll
        for (int j = 0; j < 4; ++j) {
            float da = xa[j] - ma[j];
            ma[j] += da * inv;
            sa[j] += (xa[j] - ma[j]) * da;
            float db = xb[j] - mb[j];
            mb[j] += db * inv;
            sb[j] += (xb[j] - mb[j]) * db;
        }
        n += 1.0f;
    }

    f32x4* out4 = (f32x4*)out;
    out4[c0]            = ma;   // mean block
    out4[c0 + 1]        = mb;
    out4[stride4 + c0]      = sa;   // M2 block
    out4[stride4 + c0 + 1]  = sb;
}

extern "C" void kernel_launch(void* const* d_in, const int* in_sizes, int n_in,
                              void* d_out, int out_size, void* d_ws, size_t ws_size,
                              hipStream_t stream) {
    const float* x  = (const float*)d_in[0];
    const float* m0 = (const float*)d_in[1];
    const float* s0 = (const float*)d_in[2];
    const int*   n0 = (const int*)d_in[3];
    float* out = (float*)d_out;

    const int pairs = (CHW / 4) / 2;     // 131,072 thread-pairs
    const int block = 256;
    const int grid = (pairs + block - 1) / block;  // 512 blocks -> 2/CU, 8 waves/CU
    welford_kernel<<<grid, block, 0, stream>>>(x, m0, s0, n0, out);
}